// Round 6
// baseline (174.911 us; speedup 1.0000x reference)
//
#include <hip/hip_runtime.h>

// CloudCrop fused MFMA kernel, round 6: 4 blocks/CU (LDS = 40960 exactly),
// multiplexed 8K LDS region, in-register V transpose via shfl (no bounce),
// operand-swapped A/B phases for vectorized f16x4 epilogue writes.
// B=2,S=1024,N=10000,C=128,NS=64,hidden=256.

typedef _Float16 f16;
typedef _Float16 f16x8 __attribute__((ext_vector_type(8)));
typedef _Float16 f16x4v __attribute__((ext_vector_type(4)));
typedef float f32x4 __attribute__((ext_vector_type(4)));
typedef unsigned int u32;
typedef u32 u32x2 __attribute__((ext_vector_type(2)));

constexpr int Nn = 10000;
constexpr float RAD2 = 0.05f * 0.05f;
constexpr float HMINf = -0.02f, HMAXf = 0.02f;
constexpr float INVV = 0.99999500003749968747f; // 1/sqrt(1+1e-5)

// ws layout:
//   [0, 376832): 368 weight fragment tiles (1KB: [64 lanes][8 f16])
//     WA 0..79 (mlp, K 131->160; k 0..127=feat, 128..130=xyz), WQ 80..111,
//     WV 112..239, WT 240..367
//   [376832, +5.12MB): upT (B, N, 128) f16
#define UPT_OFF 376832

// s_q (8KB) multiplex offsets (temporally disjoint users):
#define CAND_I   0      // int [4][64]          (phase 0..merge)
#define CAND_X   1024   // f16 [4][64]
#define CAND_Y   1536
#define CAND_Z   2048
#define IDX_OFF  2560   // int [64]             (merge..A)
#define CN4_OFF  2816   // int [4]
#define XYZ_OFF  2848   // f16 [64][32]         (merge..A)
// Q/attT: full [64][128B] from phase B; partials f32[64][8] @0 mid-C.

__device__ __forceinline__ int swzb(int row, int colbyte) {
    return colbyte ^ ((row & 7) << 4);
}

__global__ void prep_kernel(const float* __restrict__ mlp_w,
                            const float* __restrict__ qk_w,
                            const float* __restrict__ v_w,
                            const float* __restrict__ t_w,
                            const float* __restrict__ up,
                            unsigned char* __restrict__ ws) {
    const int blk = blockIdx.x;
    if (blk < 92) {
        const int tid = blk * 256 + threadIdx.x;  // < 368*64
        const int tile = tid >> 6, lane = tid & 63;
        const int ln = lane & 15, kg = lane >> 4;
        f16x8 v;
        if (tile < 80) {
            const int kc = tile / 16, ct = tile % 16;
            const int n = ct * 16 + ln, kb = kc * 32 + kg * 8;
            #pragma unroll
            for (int i = 0; i < 8; ++i) {
                const int k = kb + i;
                float x = (k < 128) ? mlp_w[n * 131 + 3 + k]
                        : ((k < 131) ? mlp_w[n * 131 + (k - 128)] : 0.f);
                v[i] = (f16)x;
            }
        } else if (tile < 112) {
            const int t2 = tile - 80; const int kc = t2 >> 2, ct = t2 & 3;
            const int n = ct * 16 + ln, kb = kc * 32 + kg * 8;
            #pragma unroll
            for (int i = 0; i < 8; ++i) v[i] = (f16)qk_w[n * 256 + kb + i];
        } else if (tile < 240) {
            const int t2 = tile - 112; const int kc = t2 >> 4, ct = t2 & 15;
            const int n = ct * 16 + ln, kb = kc * 32 + kg * 8;
            #pragma unroll
            for (int i = 0; i < 8; ++i) v[i] = (f16)v_w[n * 256 + kb + i];
        } else {
            const int t2 = tile - 240; const int kc = t2 >> 4, ct = t2 & 15;
            const int n = ct * 16 + ln, kb = kc * 32 + kg * 8;
            #pragma unroll
            for (int i = 0; i < 8; ++i) v[i] = (f16)t_w[n * 256 + kb + i];
        }
        *(f16x8*)(ws + (size_t)tid * 16) = v;
    } else {
        __shared__ f16 tile[64 * 136];
        const int bidx = blk - 92;
        const int b = bidx / 157;
        const int n0 = (bidx % 157) * 64;
        const int lane = threadIdx.x & 63;
        const int cw = threadIdx.x >> 6;
        const int n = n0 + lane;
        const float* upb = up + (size_t)b * 128 * Nn;
        #pragma unroll
        for (int i = 0; i < 32; ++i) {
            const int c = cw * 32 + i;
            const float x = (n < Nn) ? upb[(size_t)c * Nn + n] : 0.f;
            tile[lane * 136 + c] = (f16)x;
        }
        __syncthreads();
        f16* dst = (f16*)(ws + UPT_OFF) + (size_t)b * Nn * 128;
        #pragma unroll
        for (int p = 0; p < 4; ++p) {
            const int flat8 = threadIdx.x + p * 256;
            const int row = flat8 >> 4;
            const int c = (flat8 & 15) * 8;
            if (n0 + row < Nn)
                *(f16x8*)(dst + ((size_t)(n0 + row)) * 128 + c) =
                    *(const f16x8*)(tile + row * 136 + c);
        }
    }
}

__launch_bounds__(256, 4)
__global__ void cloudcrop_mfma(
    const float* __restrict__ seed,  // (B,S,3)
    const float* __restrict__ pc,    // (B,N,3)
    const float* __restrict__ rot,   // (B,S,3,3)
    const float* __restrict__ mlp_b,
    const float* __restrict__ bn1g,
    const float* __restrict__ bn1b,
    const float* __restrict__ v_b,
    const float* __restrict__ t_b,
    const float* __restrict__ bn2g,
    const float* __restrict__ bn2b,
    const unsigned char* __restrict__ ws,
    float* __restrict__ out)         // (B,256,S) f32
{
    __shared__ __align__(16) unsigned char s_x[64 * 512]; // X [64][256] f16 swz; Y in-place
    __shared__ __align__(16) unsigned char s_q[8192];     // multiplexed (see map above)

    int*   cand_i  = (int*)(s_q + CAND_I);
    f16*   cand_x  = (f16*)(s_q + CAND_X);
    f16*   cand_y  = (f16*)(s_q + CAND_Y);
    f16*   cand_z  = (f16*)(s_q + CAND_Z);
    int*   idx_s   = (int*)(s_q + IDX_OFF);
    int*   cand_n4 = (int*)(s_q + CN4_OFF);
    f16*   s_xyz   = (f16*)(s_q + XYZ_OFF);   // [64][32]
    float* s_part  = (float*)s_q;             // [64][8] mid-C

    const int grp = blockIdx.x;
    const int bb = grp >> 10;
    const int s  = grp & 1023;
    const int t  = threadIdx.x;
    const int lane = t & 63;
    const int w    = t >> 6;
    const int ln   = lane & 15;
    const int kg   = lane >> 4;
    const int kg16 = kg * 16;
    const int g4   = kg * 4;

    // ---------- Phase 0: selection scan, 4 waves x 2500 pts, 2x unroll ------
    {
        const float sx = seed[grp*3+0], sy = seed[grp*3+1], sz = seed[grp*3+2];
        const float R0 = rot[grp*9+0], R1 = rot[grp*9+1], R2 = rot[grp*9+2];
        const float R3 = rot[grp*9+3], R4 = rot[grp*9+4], R5 = rot[grp*9+5];
        const float R6 = rot[grp*9+6], R7 = rot[grp*9+7], R8 = rot[grp*9+8];
        const unsigned long long lmask = (1ull << lane) - 1ull;
        int count = 0;
        const int lo = w * 2500, hi = lo + 2500;
        for (int base = lo; base < hi; base += 128) {
            const int n0i = base + lane, n1i = base + 64 + lane;
            bool m0 = false, m1 = false;
            float rx0=0.f, ry0=0.f, rz0=0.f, rx1=0.f, ry1=0.f, rz1=0.f;
            if (n0i < hi) {
                const float px = pc[(bb*Nn + n0i)*3+0] - sx;
                const float py = pc[(bb*Nn + n0i)*3+1] - sy;
                const float pz = pc[(bb*Nn + n0i)*3+2] - sz;
                rx0 = px*R0 + py*R3 + pz*R6;
                ry0 = px*R1 + py*R4 + pz*R7;
                rz0 = px*R2 + py*R5 + pz*R8;
                m0 = (ry0*ry0 + rz0*rz0 < RAD2) && (rx0 > HMINf) && (rx0 < HMAXf);
            }
            if (n1i < hi) {
                const float px = pc[(bb*Nn + n1i)*3+0] - sx;
                const float py = pc[(bb*Nn + n1i)*3+1] - sy;
                const float pz = pc[(bb*Nn + n1i)*3+2] - sz;
                rx1 = px*R0 + py*R3 + pz*R6;
                ry1 = px*R1 + py*R4 + pz*R7;
                rz1 = px*R2 + py*R5 + pz*R8;
                m1 = (ry1*ry1 + rz1*rz1 < RAD2) && (rx1 > HMINf) && (rx1 < HMAXf);
            }
            const unsigned long long bal0 = __ballot(m0);
            const unsigned long long bal1 = __ballot(m1);
            const int c0 = __popcll(bal0);
            const int pos0 = count + __popcll(bal0 & lmask);
            const int pos1 = count + c0 + __popcll(bal1 & lmask);
            if (m0 && pos0 < 64) {
                cand_i[w*64 + pos0] = n0i;
                cand_x[w*64 + pos0] = (f16)rx0; cand_y[w*64 + pos0] = (f16)ry0;
                cand_z[w*64 + pos0] = (f16)rz0;
            }
            if (m1 && pos1 < 64) {
                cand_i[w*64 + pos1] = n1i;
                cand_x[w*64 + pos1] = (f16)rx1; cand_y[w*64 + pos1] = (f16)ry1;
                cand_z[w*64 + pos1] = (f16)rz1;
            }
            count += c0 + __popcll(bal1);
        }
        if (lane == 0) cand_n4[w] = count < 64 ? count : 64;
    }
    __syncthreads();

    // ---------- Merge (ordered) -> idx_s + xyz tile -------------------------
    if (t < 64) {
        const int c0 = cand_n4[0], c1 = cand_n4[1], c2 = cand_n4[2], c3 = cand_n4[3];
        const int o1 = c0, o2 = c0 + c1, o3 = o2 + c2;
        int total = o3 + c3; if (total > 64) total = 64;
        int myi; f16 hx, hy, hz;
        if (total > 0) {
            const int pp = (t < total) ? t : 0;
            int sw_, sq;
            if      (pp >= o3) { sw_ = 3; sq = pp - o3; }
            else if (pp >= o2) { sw_ = 2; sq = pp - o2; }
            else if (pp >= o1) { sw_ = 1; sq = pp - o1; }
            else               { sw_ = 0; sq = pp; }
            myi = cand_i[sw_*64 + sq];
            hx = cand_x[sw_*64 + sq]; hy = cand_y[sw_*64 + sq]; hz = cand_z[sw_*64 + sq];
        } else {
            const float sx = seed[grp*3+0], sy = seed[grp*3+1], sz = seed[grp*3+2];
            const float px = pc[(bb*Nn)*3+0] - sx;
            const float py = pc[(bb*Nn)*3+1] - sy;
            const float pz = pc[(bb*Nn)*3+2] - sz;
            hx = (f16)(px*rot[grp*9+0] + py*rot[grp*9+3] + pz*rot[grp*9+6]);
            hy = (f16)(px*rot[grp*9+1] + py*rot[grp*9+4] + pz*rot[grp*9+7]);
            hz = (f16)(px*rot[grp*9+2] + py*rot[grp*9+5] + pz*rot[grp*9+8]);
            myi = 0;
        }
        idx_s[t] = myi;
        f16x8 z0 = {};
        z0[0] = hx; z0[1] = hy; z0[2] = hz;
        f16x8 zz = {};
        f16x8* xr = (f16x8*)(s_xyz + t * 32);
        xr[0] = z0; xr[1] = zz; xr[2] = zz; xr[3] = zz;
    }
    __syncthreads();

    // ---------- Phase A (swapped): H = WA @ [feat|xyz]^T -> X ---------------
    // mfma(A=weight frag, B=sample frag): out col=sample, rows=4 consec chans
    {
        int idxr[4];
        #pragma unroll
        for (int nt = 0; nt < 4; ++nt) idxr[nt] = idx_s[nt*16 + ln];
        const f16* upTb = (const f16*)(ws + UPT_OFF) + (size_t)bb * Nn * 128;

        f32x4 acc[4][4] = {};   // [ch-tile jt][sample-tile nt]
        #pragma unroll
        for (int kc = 0; kc < 4; ++kc) {
            f16x8 bX[4];
            #pragma unroll
            for (int nt = 0; nt < 4; ++nt)
                bX[nt] = *(const f16x8*)(upTb + (size_t)idxr[nt]*128 + kc*32 + kg*8);
            #pragma unroll
            for (int jt = 0; jt < 4; ++jt) {
                const f16x8 aw = *(const f16x8*)(ws + (size_t)(kc*16 + 4*w + jt)*1024 + lane*16);
                #pragma unroll
                for (int nt = 0; nt < 4; ++nt)
                    acc[jt][nt] = __builtin_amdgcn_mfma_f32_16x16x32_f16(aw, bX[nt], acc[jt][nt], 0, 0, 0);
            }
        }
        {   // kc = 4: xyz from LDS
            f16x8 bX[4];
            #pragma unroll
            for (int nt = 0; nt < 4; ++nt)
                bX[nt] = *(const f16x8*)(s_xyz + (nt*16 + ln)*32 + kg*8);
            #pragma unroll
            for (int jt = 0; jt < 4; ++jt) {
                const f16x8 aw = *(const f16x8*)(ws + (size_t)(64 + 4*w + jt)*1024 + lane*16);
                #pragma unroll
                for (int nt = 0; nt < 4; ++nt)
                    acc[jt][nt] = __builtin_amdgcn_mfma_f32_16x16x32_f16(aw, bX[nt], acc[jt][nt], 0, 0, 0);
            }
        }
        #pragma unroll
        for (int jt = 0; jt < 4; ++jt) {
            const int chb = (4*w + jt)*16 + g4;
            const f32x4 mb4 = *(const f32x4*)(mlp_b + chb);
            const f32x4 g14 = *(const f32x4*)(bn1g + chb);
            const f32x4 b14 = *(const f32x4*)(bn1b + chb);
            #pragma unroll
            for (int nt = 0; nt < 4; ++nt) {
                const int smp = nt*16 + ln;
                f16x4v hv;
                #pragma unroll
                for (int r = 0; r < 4; ++r)
                    hv[r] = (f16)fmaxf((acc[jt][nt][r] + mb4[r]) * (g14[r]*INVV) + b14[r], 0.f);
                *(f16x4v*)(s_x + smp*512 + swzb(smp, chb*2)) = hv;
            }
        }
    }
    __syncthreads();   // also covers s_q reuse: xyz/cand dead, Q next

    // ---------- Phase B (swapped): Q = WQ @ X^T -> Q[smp][qch] --------------
    {
        f32x4 accq[4] = {};   // [nt]
        #pragma unroll
        for (int kc = 0; kc < 8; ++kc) {
            const f16x8 aw = *(const f16x8*)(ws + (size_t)(80 + kc*4 + w)*1024 + lane*16);
            #pragma unroll
            for (int nt = 0; nt < 4; ++nt) {
                const int row = nt*16 + ln;
                const f16x8 bX = *(const f16x8*)(s_x + row*512 + swzb(row, kc*64 + kg16));
                accq[nt] = __builtin_amdgcn_mfma_f32_16x16x32_f16(aw, bX, accq[nt], 0, 0, 0);
            }
        }
        const int qb = (w*16 + g4) * 2;   // byte offset of 4 consec qch
        #pragma unroll
        for (int nt = 0; nt < 4; ++nt) {
            const int smp = nt*16 + ln;
            f16x4v pk;
            #pragma unroll
            for (int r = 0; r < 4; ++r) pk[r] = (f16)accq[nt][r];
            *(f16x4v*)(s_q + smp*128 + swzb(smp, qb)) = pk;
        }
    }
    __syncthreads();

    // ---------- Phase C: S = Q @ Q^T; partial softmax (s_q-resident) --------
    f32x4 accs[4];
    {
        #pragma unroll
        for (int rt = 0; rt < 4; ++rt) accs[rt] = (f32x4){0.f,0.f,0.f,0.f};
        #pragma unroll
        for (int kc = 0; kc < 2; ++kc) {
            const int rowb = w*16 + ln;
            const f16x8 bQ = *(const f16x8*)(s_q + rowb*128 + swzb(rowb, kc*64 + kg16));
            #pragma unroll
            for (int rt = 0; rt < 4; ++rt) {
                const int row = rt*16 + ln;
                const f16x8 aQ = *(const f16x8*)(s_q + row*128 + swzb(row, kc*64 + kg16));
                accs[rt] = __builtin_amdgcn_mfma_f32_16x16x32_f16(aQ, bQ, accs[rt], 0, 0, 0);
            }
        }
    }
    __syncthreads();   // all Q reads done before partials overwrite s_q[0..2K)
    {
        float pm[4][4];
        #pragma unroll
        for (int rt = 0; rt < 4; ++rt)
            #pragma unroll
            for (int r = 0; r < 4; ++r) {
                float v = accs[rt][r];
                float mx = fmaxf(v, __shfl_xor(v, 1));
                mx = fmaxf(mx, __shfl_xor(mx, 2));
                mx = fmaxf(mx, __shfl_xor(mx, 4));
                mx = fmaxf(mx, __shfl_xor(mx, 8));
                pm[rt][r] = mx;
                const float e = __expf(v - mx);
                accs[rt][r] = e;
                float sm = e + __shfl_xor(e, 1);
                sm += __shfl_xor(sm, 2);
                sm += __shfl_xor(sm, 4);
                sm += __shfl_xor(sm, 8);
                if (ln == 0) {
                    const int row = rt*16 + g4 + r;
                    s_part[row*8 + w*2 + 0] = mx;
                    s_part[row*8 + w*2 + 1] = sm;
                }
            }
        __syncthreads();
        float sc[4][4];
        #pragma unroll
        for (int rt = 0; rt < 4; ++rt)
            #pragma unroll
            for (int r = 0; r < 4; ++r) {
                const int row = rt*16 + g4 + r;    // same addr across ln: broadcast
                const f32x4 pa = *(const f32x4*)(s_part + row*8);
                const f32x4 pb = *(const f32x4*)(s_part + row*8 + 4);
                const float fm = fmaxf(fmaxf(pa.x, pa.z), fmaxf(pb.x, pb.z));
                const float den = pa.y*__expf(pa.x - fm) + pa.w*__expf(pa.z - fm)
                                + pb.y*__expf(pb.x - fm) + pb.w*__expf(pb.z - fm);
                sc[rt][r] = __expf(pm[rt][r] - fm) / den;
            }
        __syncthreads();   // partials consumed before attT overwrites s_q
        const int arow = w*16 + ln;
        #pragma unroll
        for (int rt = 0; rt < 4; ++rt) {
            f16x4v pk;
            #pragma unroll
            for (int r = 0; r < 4; ++r) pk[r] = (f16)(accs[rt][r] * sc[rt][r]);
            *(f16x4v*)(s_q + arow*128 + swzb(arow, (rt*16 + g4)*2)) = pk;
        }
    }
    __syncthreads();

    // ---------- Phase D: V=X@WV+vb; in-reg transpose via shfl; XR=attT@V ----
    f32x4 accr[4][4];
    f32x4 accONE[4];
    {
        f16x8 a2[2][4];
        #pragma unroll
        for (int kc = 0; kc < 2; ++kc)
            #pragma unroll
            for (int rt = 0; rt < 4; ++rt) {
                const int row = rt*16 + ln;
                a2[kc][rt] = *(const f16x8*)(s_q + row*128 + swzb(row, kc*64 + kg16));
            }
        // colsum via ones-MFMA (same C/D row layout as accr)
        f16x8 onef;
        #pragma unroll
        for (int i = 0; i < 8; ++i) onef[i] = (f16)1.0f;
        #pragma unroll
        for (int rt = 0; rt < 4; ++rt) accONE[rt] = (f32x4){0.f,0.f,0.f,0.f};
        #pragma unroll
        for (int kc = 0; kc < 2; ++kc)
            #pragma unroll
            for (int rt = 0; rt < 4; ++rt)
                accONE[rt] = __builtin_amdgcn_mfma_f32_16x16x32_f16(a2[kc][rt], onef, accONE[rt], 0, 0, 0);

        #pragma unroll
        for (int rt = 0; rt < 4; ++rt)
            #pragma unroll
            for (int j = 0; j < 4; ++j) accr[rt][j] = (f32x4){0.f,0.f,0.f,0.f};

        const int sbase = ln + ((lane >> 4) & 1) * 32;   // shfl src base
        const bool hiHalf = (kg >= 2);
        #pragma unroll
        for (int j = 0; j < 4; ++j) {
            const float vb = v_b[(4*w + j)*16 + ln];
            f32x4 accv[4] = {};
            #pragma unroll 2
            for (int kc = 0; kc < 8; ++kc) {
                const f16x8 bf = *(const f16x8*)(ws + (size_t)(112 + kc*16 + 4*w + j)*1024 + lane*16);
                #pragma unroll
                for (int rt = 0; rt < 4; ++rt) {
                    const int row = rt*16 + ln;
                    const f16x8 aX = *(const f16x8*)(s_x + row*512 + swzb(row, kc*64 + kg16));
                    accv[rt] = __builtin_amdgcn_mfma_f32_16x16x32_f16(aX, bf, accv[rt], 0, 0, 0);
                }
            }
            // pack to f16 pairs: pk[rt][p] = samples rt*16+g4+{2p,2p+1}
            u32 pk[4][2];
            #pragma unroll
            for (int rt = 0; rt < 4; ++rt) {
                f16x4v v4;
                #pragma unroll
                for (int r = 0; r < 4; ++r) v4[r] = (f16)(accv[rt][r] + vb);
                const u32x2 p2 = __builtin_bit_cast(u32x2, v4);
                pk[rt][0] = p2.x; pk[rt][1] = p2.y;
            }
            // route: B-frag reg q <- lane (sbase + 16*(q>>1)), pk[2kc+(kg>>1)][q&1]
            #pragma unroll
            for (int kc = 0; kc < 2; ++kc) {
                union { u32 u[4]; f16x8 v; } bu;
                #pragma unroll
                for (int q = 0; q < 4; ++q) {
                    const int srcl = sbase + 16*(q >> 1);
                    const u32 lo = (u32)__shfl((int)pk[2*kc + 0][q & 1], srcl);
                    const u32 hi = (u32)__shfl((int)pk[2*kc + 1][q & 1], srcl);
                    bu.u[q] = hiHalf ? hi : lo;
                }
                #pragma unroll
                for (int rt = 0; rt < 4; ++rt)
                    accr[rt][j] = __builtin_amdgcn_mfma_f32_16x16x32_f16(a2[kc][rt], bu.v, accr[rt][j], 0, 0, 0);
            }
        }
    }
    __syncthreads();  // all waves' X reads done before Y overwrite

    // ---------- D-epilogue: Y = X - XR/colsum (in-place), keep X in regs ----
    f16x4v xsave[4][4];
    {
        float rinv[4][4];
        #pragma unroll
        for (int rt = 0; rt < 4; ++rt)
            #pragma unroll
            for (int r = 0; r < 4; ++r)
                rinv[rt][r] = __builtin_amdgcn_rcpf(1e-9f + accONE[rt][r]);
        #pragma unroll
        for (int j = 0; j < 4; ++j) {
            const int col = (4*w + j)*16 + ln;
            #pragma unroll
            for (int rt = 0; rt < 4; ++rt) {
                f16x4v xs4;
                #pragma unroll
                for (int r = 0; r < 4; ++r) {
                    const int row = rt*16 + g4 + r;
                    const f16 xv = *(const f16*)(s_x + row*512 + swzb(row, col*2));
                    xs4[r] = xv;
                    const float yv = (float)xv - accr[rt][j][r] * rinv[rt][r];
                    *(f16*)(s_x + row*512 + swzb(row, col*2)) = (f16)yv;
                }
                xsave[j][rt] = xs4;
            }
        }
    }
    __syncthreads();

    // ---------- Phase E: T = Y @ WT + t_b; out = maxpool(X + relu(BN2)) -----
    {
        f32x4 acct[4][4] = {};
        #pragma unroll 2
        for (int kc = 0; kc < 8; ++kc) {
            f16x8 a[4];
            #pragma unroll
            for (int rt = 0; rt < 4; ++rt) {
                const int row = rt*16 + ln;
                a[rt] = *(const f16x8*)(s_x + row*512 + swzb(row, kc*64 + kg16));  // Y
            }
            #pragma unroll
            for (int j = 0; j < 4; ++j) {
                const f16x8 bf = *(const f16x8*)(ws + (size_t)(240 + kc*16 + 4*w + j)*1024 + lane*16);
                #pragma unroll
                for (int rt = 0; rt < 4; ++rt)
                    acct[rt][j] = __builtin_amdgcn_mfma_f32_16x16x32_f16(a[rt], bf, acct[rt][j], 0, 0, 0);
            }
        }
        #pragma unroll
        for (int j = 0; j < 4; ++j) {
            const int col = (4*w + j)*16 + ln;
            const float tb = t_b[col], g2 = bn2g[col]*INVV, b2 = bn2b[col];
            float m = -3.4e38f;
            #pragma unroll
            for (int rt = 0; rt < 4; ++rt)
                #pragma unroll
                for (int r = 0; r < 4; ++r) {
                    const float tv = acct[rt][j][r] + tb;
                    const float rl = fmaxf(tv*g2 + b2, 0.f);
                    const float xv = (float)xsave[j][rt][r];
                    m = fmaxf(m, xv + rl);
                }
            m = fmaxf(m, __shfl_xor(m, 16));
            m = fmaxf(m, __shfl_xor(m, 32));
            if (kg == 0)
                out[((size_t)bb*256 + col)*1024 + s] = m;
        }
    }
}

extern "C" void kernel_launch(void* const* d_in, const int* in_sizes, int n_in,
                              void* d_out, int out_size, void* d_ws, size_t ws_size,
                              hipStream_t stream) {
    (void)in_sizes; (void)n_in; (void)out_size; (void)ws_size;
    unsigned char* ws = (unsigned char*)d_ws;
    prep_kernel<<<92 + 314, 256, 0, stream>>>(
        (const float*)d_in[4],   // mlp_w
        (const float*)d_in[8],   // qk_w
        (const float*)d_in[9],   // v_w
        (const float*)d_in[11],  // t_w
        (const float*)d_in[3],   // up_feature
        ws);
    cloudcrop_mfma<<<2048, 256, 0, stream>>>(
        (const float*)d_in[0],   // seed_xyz
        (const float*)d_in[1],   // pointcloud
        (const float*)d_in[2],   // vp_rot
        (const float*)d_in[5],   // mlp_b
        (const float*)d_in[6],   // bn1_g
        (const float*)d_in[7],   // bn1_b
        (const float*)d_in[10],  // v_b
        (const float*)d_in[12],  // t_b
        (const float*)d_in[13],  // bn2_g
        (const float*)d_in[14],  // bn2_b
        ws,
        (float*)d_out);
}

// Round 7
// 148.247 us; speedup vs baseline: 1.1799x; 1.1799x over previous
//
#include <hip/hip_runtime.h>

// CloudCrop fused MFMA kernel, round 7: R6 structure (in-reg shfl V-transpose,
// vectorized epilogues, 40KB multiplexed LDS) at launch_bounds(256,3) to stay
// spill-free (R4/R6 lesson: spills cost more than occupancy buys).
// B=2,S=1024,N=10000,C=128,NS=64,hidden=256.

typedef _Float16 f16;
typedef _Float16 f16x8 __attribute__((ext_vector_type(8)));
typedef _Float16 f16x4v __attribute__((ext_vector_type(4)));
typedef float f32x4 __attribute__((ext_vector_type(4)));
typedef unsigned int u32;
typedef u32 u32x2 __attribute__((ext_vector_type(2)));

constexpr int Nn = 10000;
constexpr float RAD2 = 0.05f * 0.05f;
constexpr float HMINf = -0.02f, HMAXf = 0.02f;
constexpr float INVV = 0.99999500003749968747f; // 1/sqrt(1+1e-5)

// ws layout:
//   [0, 376832): 368 weight fragment tiles (1KB: [64 lanes][8 f16])
//     WA 0..79 (mlp, K 131->160; k 0..127=feat, 128..130=xyz), WQ 80..111,
//     WV 112..239, WT 240..367
//   [376832, +5.12MB): upT (B, N, 128) f16
#define UPT_OFF 376832

// s_q (8KB) multiplex offsets (temporally disjoint users):
#define CAND_I   0      // int [4][64]          (phase 0..merge)
#define CAND_X   1024   // f16 [4][64]
#define CAND_Y   1536
#define CAND_Z   2048
#define IDX_OFF  2560   // int [64]             (merge..A)
#define CN4_OFF  2816   // int [4]
#define XYZ_OFF  2848   // f16 [64][32]         (merge..A)
// Q/attT: full [64][128B] from phase B; partials f32[64][8] @0 mid-C.

__device__ __forceinline__ int swzb(int row, int colbyte) {
    return colbyte ^ ((row & 7) << 4);
}

__global__ void prep_kernel(const float* __restrict__ mlp_w,
                            const float* __restrict__ qk_w,
                            const float* __restrict__ v_w,
                            const float* __restrict__ t_w,
                            const float* __restrict__ up,
                            unsigned char* __restrict__ ws) {
    const int blk = blockIdx.x;
    if (blk < 92) {
        const int tid = blk * 256 + threadIdx.x;  // < 368*64
        const int tile = tid >> 6, lane = tid & 63;
        const int ln = lane & 15, kg = lane >> 4;
        f16x8 v;
        if (tile < 80) {
            const int kc = tile / 16, ct = tile % 16;
            const int n = ct * 16 + ln, kb = kc * 32 + kg * 8;
            #pragma unroll
            for (int i = 0; i < 8; ++i) {
                const int k = kb + i;
                float x = (k < 128) ? mlp_w[n * 131 + 3 + k]
                        : ((k < 131) ? mlp_w[n * 131 + (k - 128)] : 0.f);
                v[i] = (f16)x;
            }
        } else if (tile < 112) {
            const int t2 = tile - 80; const int kc = t2 >> 2, ct = t2 & 3;
            const int n = ct * 16 + ln, kb = kc * 32 + kg * 8;
            #pragma unroll
            for (int i = 0; i < 8; ++i) v[i] = (f16)qk_w[n * 256 + kb + i];
        } else if (tile < 240) {
            const int t2 = tile - 112; const int kc = t2 >> 4, ct = t2 & 15;
            const int n = ct * 16 + ln, kb = kc * 32 + kg * 8;
            #pragma unroll
            for (int i = 0; i < 8; ++i) v[i] = (f16)v_w[n * 256 + kb + i];
        } else {
            const int t2 = tile - 240; const int kc = t2 >> 4, ct = t2 & 15;
            const int n = ct * 16 + ln, kb = kc * 32 + kg * 8;
            #pragma unroll
            for (int i = 0; i < 8; ++i) v[i] = (f16)t_w[n * 256 + kb + i];
        }
        *(f16x8*)(ws + (size_t)tid * 16) = v;
    } else {
        __shared__ f16 tile[64 * 136];
        const int bidx = blk - 92;
        const int b = bidx / 157;
        const int n0 = (bidx % 157) * 64;
        const int lane = threadIdx.x & 63;
        const int cw = threadIdx.x >> 6;
        const int n = n0 + lane;
        const float* upb = up + (size_t)b * 128 * Nn;
        #pragma unroll
        for (int i = 0; i < 32; ++i) {
            const int c = cw * 32 + i;
            const float x = (n < Nn) ? upb[(size_t)c * Nn + n] : 0.f;
            tile[lane * 136 + c] = (f16)x;
        }
        __syncthreads();
        f16* dst = (f16*)(ws + UPT_OFF) + (size_t)b * Nn * 128;
        #pragma unroll
        for (int p = 0; p < 4; ++p) {
            const int flat8 = threadIdx.x + p * 256;
            const int row = flat8 >> 4;
            const int c = (flat8 & 15) * 8;
            if (n0 + row < Nn)
                *(f16x8*)(dst + ((size_t)(n0 + row)) * 128 + c) =
                    *(const f16x8*)(tile + row * 136 + c);
        }
    }
}

__launch_bounds__(256, 3)
__global__ void cloudcrop_mfma(
    const float* __restrict__ seed,  // (B,S,3)
    const float* __restrict__ pc,    // (B,N,3)
    const float* __restrict__ rot,   // (B,S,3,3)
    const float* __restrict__ mlp_b,
    const float* __restrict__ bn1g,
    const float* __restrict__ bn1b,
    const float* __restrict__ v_b,
    const float* __restrict__ t_b,
    const float* __restrict__ bn2g,
    const float* __restrict__ bn2b,
    const unsigned char* __restrict__ ws,
    float* __restrict__ out)         // (B,256,S) f32
{
    __shared__ __align__(16) unsigned char s_x[64 * 512]; // X [64][256] f16 swz; Y in-place
    __shared__ __align__(16) unsigned char s_q[8192];     // multiplexed (see map above)

    int*   cand_i  = (int*)(s_q + CAND_I);
    f16*   cand_x  = (f16*)(s_q + CAND_X);
    f16*   cand_y  = (f16*)(s_q + CAND_Y);
    f16*   cand_z  = (f16*)(s_q + CAND_Z);
    int*   idx_s   = (int*)(s_q + IDX_OFF);
    int*   cand_n4 = (int*)(s_q + CN4_OFF);
    f16*   s_xyz   = (f16*)(s_q + XYZ_OFF);   // [64][32]
    float* s_part  = (float*)s_q;             // [64][8] mid-C

    const int grp = blockIdx.x;
    const int bb = grp >> 10;
    const int s  = grp & 1023;
    const int t  = threadIdx.x;
    const int lane = t & 63;
    const int w    = t >> 6;
    const int ln   = lane & 15;
    const int kg   = lane >> 4;
    const int kg16 = kg * 16;
    const int g4   = kg * 4;

    // ---------- Phase 0: selection scan, 4 waves x 2500 pts, 2x unroll ------
    {
        const float sx = seed[grp*3+0], sy = seed[grp*3+1], sz = seed[grp*3+2];
        const float R0 = rot[grp*9+0], R1 = rot[grp*9+1], R2 = rot[grp*9+2];
        const float R3 = rot[grp*9+3], R4 = rot[grp*9+4], R5 = rot[grp*9+5];
        const float R6 = rot[grp*9+6], R7 = rot[grp*9+7], R8 = rot[grp*9+8];
        const unsigned long long lmask = (1ull << lane) - 1ull;
        int count = 0;
        const int lo = w * 2500, hi = lo + 2500;
        for (int base = lo; base < hi; base += 128) {
            const int n0i = base + lane, n1i = base + 64 + lane;
            bool m0 = false, m1 = false;
            float rx0=0.f, ry0=0.f, rz0=0.f, rx1=0.f, ry1=0.f, rz1=0.f;
            if (n0i < hi) {
                const float px = pc[(bb*Nn + n0i)*3+0] - sx;
                const float py = pc[(bb*Nn + n0i)*3+1] - sy;
                const float pz = pc[(bb*Nn + n0i)*3+2] - sz;
                rx0 = px*R0 + py*R3 + pz*R6;
                ry0 = px*R1 + py*R4 + pz*R7;
                rz0 = px*R2 + py*R5 + pz*R8;
                m0 = (ry0*ry0 + rz0*rz0 < RAD2) && (rx0 > HMINf) && (rx0 < HMAXf);
            }
            if (n1i < hi) {
                const float px = pc[(bb*Nn + n1i)*3+0] - sx;
                const float py = pc[(bb*Nn + n1i)*3+1] - sy;
                const float pz = pc[(bb*Nn + n1i)*3+2] - sz;
                rx1 = px*R0 + py*R3 + pz*R6;
                ry1 = px*R1 + py*R4 + pz*R7;
                rz1 = px*R2 + py*R5 + pz*R8;
                m1 = (ry1*ry1 + rz1*rz1 < RAD2) && (rx1 > HMINf) && (rx1 < HMAXf);
            }
            const unsigned long long bal0 = __ballot(m0);
            const unsigned long long bal1 = __ballot(m1);
            const int c0 = __popcll(bal0);
            const int pos0 = count + __popcll(bal0 & lmask);
            const int pos1 = count + c0 + __popcll(bal1 & lmask);
            if (m0 && pos0 < 64) {
                cand_i[w*64 + pos0] = n0i;
                cand_x[w*64 + pos0] = (f16)rx0; cand_y[w*64 + pos0] = (f16)ry0;
                cand_z[w*64 + pos0] = (f16)rz0;
            }
            if (m1 && pos1 < 64) {
                cand_i[w*64 + pos1] = n1i;
                cand_x[w*64 + pos1] = (f16)rx1; cand_y[w*64 + pos1] = (f16)ry1;
                cand_z[w*64 + pos1] = (f16)rz1;
            }
            count += c0 + __popcll(bal1);
        }
        if (lane == 0) cand_n4[w] = count < 64 ? count : 64;
    }
    __syncthreads();

    // ---------- Merge (ordered) -> idx_s + xyz tile -------------------------
    if (t < 64) {
        const int c0 = cand_n4[0], c1 = cand_n4[1], c2 = cand_n4[2], c3 = cand_n4[3];
        const int o1 = c0, o2 = c0 + c1, o3 = o2 + c2;
        int total = o3 + c3; if (total > 64) total = 64;
        int myi; f16 hx, hy, hz;
        if (total > 0) {
            const int pp = (t < total) ? t : 0;
            int sw_, sq;
            if      (pp >= o3) { sw_ = 3; sq = pp - o3; }
            else if (pp >= o2) { sw_ = 2; sq = pp - o2; }
            else if (pp >= o1) { sw_ = 1; sq = pp - o1; }
            else               { sw_ = 0; sq = pp; }
            myi = cand_i[sw_*64 + sq];
            hx = cand_x[sw_*64 + sq]; hy = cand_y[sw_*64 + sq]; hz = cand_z[sw_*64 + sq];
        } else {
            const float sx = seed[grp*3+0], sy = seed[grp*3+1], sz = seed[grp*3+2];
            const float px = pc[(bb*Nn)*3+0] - sx;
            const float py = pc[(bb*Nn)*3+1] - sy;
            const float pz = pc[(bb*Nn)*3+2] - sz;
            hx = (f16)(px*rot[grp*9+0] + py*rot[grp*9+3] + pz*rot[grp*9+6]);
            hy = (f16)(px*rot[grp*9+1] + py*rot[grp*9+4] + pz*rot[grp*9+7]);
            hz = (f16)(px*rot[grp*9+2] + py*rot[grp*9+5] + pz*rot[grp*9+8]);
            myi = 0;
        }
        idx_s[t] = myi;
        f16x8 z0 = {};
        z0[0] = hx; z0[1] = hy; z0[2] = hz;
        f16x8 zz = {};
        f16x8* xr = (f16x8*)(s_xyz + t * 32);
        xr[0] = z0; xr[1] = zz; xr[2] = zz; xr[3] = zz;
    }
    __syncthreads();

    // ---------- Phase A (swapped): H = WA @ [feat|xyz]^T -> X ---------------
    {
        int idxr[4];
        #pragma unroll
        for (int nt = 0; nt < 4; ++nt) idxr[nt] = idx_s[nt*16 + ln];
        const f16* upTb = (const f16*)(ws + UPT_OFF) + (size_t)bb * Nn * 128;

        f32x4 acc[4][4] = {};   // [ch-tile jt][sample-tile nt]
        #pragma unroll
        for (int kc = 0; kc < 4; ++kc) {
            f16x8 bX[4];
            #pragma unroll
            for (int nt = 0; nt < 4; ++nt)
                bX[nt] = *(const f16x8*)(upTb + (size_t)idxr[nt]*128 + kc*32 + kg*8);
            #pragma unroll
            for (int jt = 0; jt < 4; ++jt) {
                const f16x8 aw = *(const f16x8*)(ws + (size_t)(kc*16 + 4*w + jt)*1024 + lane*16);
                #pragma unroll
                for (int nt = 0; nt < 4; ++nt)
                    acc[jt][nt] = __builtin_amdgcn_mfma_f32_16x16x32_f16(aw, bX[nt], acc[jt][nt], 0, 0, 0);
            }
        }
        {   // kc = 4: xyz from LDS
            f16x8 bX[4];
            #pragma unroll
            for (int nt = 0; nt < 4; ++nt)
                bX[nt] = *(const f16x8*)(s_xyz + (nt*16 + ln)*32 + kg*8);
            #pragma unroll
            for (int jt = 0; jt < 4; ++jt) {
                const f16x8 aw = *(const f16x8*)(ws + (size_t)(64 + 4*w + jt)*1024 + lane*16);
                #pragma unroll
                for (int nt = 0; nt < 4; ++nt)
                    acc[jt][nt] = __builtin_amdgcn_mfma_f32_16x16x32_f16(aw, bX[nt], acc[jt][nt], 0, 0, 0);
            }
        }
        #pragma unroll
        for (int jt = 0; jt < 4; ++jt) {
            const int chb = (4*w + jt)*16 + g4;
            const f32x4 mb4 = *(const f32x4*)(mlp_b + chb);
            const f32x4 g14 = *(const f32x4*)(bn1g + chb);
            const f32x4 b14 = *(const f32x4*)(bn1b + chb);
            #pragma unroll
            for (int nt = 0; nt < 4; ++nt) {
                const int smp = nt*16 + ln;
                f16x4v hv;
                #pragma unroll
                for (int r = 0; r < 4; ++r)
                    hv[r] = (f16)fmaxf((acc[jt][nt][r] + mb4[r]) * (g14[r]*INVV) + b14[r], 0.f);
                *(f16x4v*)(s_x + smp*512 + swzb(smp, chb*2)) = hv;
            }
        }
    }
    __syncthreads();   // also covers s_q reuse: xyz/cand dead, Q next

    // ---------- Phase B (swapped): Q = WQ @ X^T -> Q[smp][qch] --------------
    {
        f32x4 accq[4] = {};   // [nt]
        #pragma unroll
        for (int kc = 0; kc < 8; ++kc) {
            const f16x8 aw = *(const f16x8*)(ws + (size_t)(80 + kc*4 + w)*1024 + lane*16);
            #pragma unroll
            for (int nt = 0; nt < 4; ++nt) {
                const int row = nt*16 + ln;
                const f16x8 bX = *(const f16x8*)(s_x + row*512 + swzb(row, kc*64 + kg16));
                accq[nt] = __builtin_amdgcn_mfma_f32_16x16x32_f16(aw, bX, accq[nt], 0, 0, 0);
            }
        }
        const int qb = (w*16 + g4) * 2;   // byte offset of 4 consec qch
        #pragma unroll
        for (int nt = 0; nt < 4; ++nt) {
            const int smp = nt*16 + ln;
            f16x4v pk;
            #pragma unroll
            for (int r = 0; r < 4; ++r) pk[r] = (f16)accq[nt][r];
            *(f16x4v*)(s_q + smp*128 + swzb(smp, qb)) = pk;
        }
    }
    __syncthreads();

    // ---------- Phase C: S = Q @ Q^T; partial softmax (s_q-resident) --------
    f32x4 accs[4];
    {
        #pragma unroll
        for (int rt = 0; rt < 4; ++rt) accs[rt] = (f32x4){0.f,0.f,0.f,0.f};
        #pragma unroll
        for (int kc = 0; kc < 2; ++kc) {
            const int rowb = w*16 + ln;
            const f16x8 bQ = *(const f16x8*)(s_q + rowb*128 + swzb(rowb, kc*64 + kg16));
            #pragma unroll
            for (int rt = 0; rt < 4; ++rt) {
                const int row = rt*16 + ln;
                const f16x8 aQ = *(const f16x8*)(s_q + row*128 + swzb(row, kc*64 + kg16));
                accs[rt] = __builtin_amdgcn_mfma_f32_16x16x32_f16(aQ, bQ, accs[rt], 0, 0, 0);
            }
        }
    }
    __syncthreads();   // all Q reads done before partials overwrite s_q[0..2K)
    {
        float pm[4][4];
        #pragma unroll
        for (int rt = 0; rt < 4; ++rt)
            #pragma unroll
            for (int r = 0; r < 4; ++r) {
                float v = accs[rt][r];
                float mx = fmaxf(v, __shfl_xor(v, 1));
                mx = fmaxf(mx, __shfl_xor(mx, 2));
                mx = fmaxf(mx, __shfl_xor(mx, 4));
                mx = fmaxf(mx, __shfl_xor(mx, 8));
                pm[rt][r] = mx;
                const float e = __expf(v - mx);
                accs[rt][r] = e;
                float sm = e + __shfl_xor(e, 1);
                sm += __shfl_xor(sm, 2);
                sm += __shfl_xor(sm, 4);
                sm += __shfl_xor(sm, 8);
                if (ln == 0) {
                    const int row = rt*16 + g4 + r;
                    s_part[row*8 + w*2 + 0] = mx;
                    s_part[row*8 + w*2 + 1] = sm;
                }
            }
        __syncthreads();
        float sc[4][4];
        #pragma unroll
        for (int rt = 0; rt < 4; ++rt)
            #pragma unroll
            for (int r = 0; r < 4; ++r) {
                const int row = rt*16 + g4 + r;    // same addr across ln: broadcast
                const f32x4 pa = *(const f32x4*)(s_part + row*8);
                const f32x4 pb = *(const f32x4*)(s_part + row*8 + 4);
                const float fm = fmaxf(fmaxf(pa.x, pa.z), fmaxf(pb.x, pb.z));
                const float den = pa.y*__expf(pa.x - fm) + pa.w*__expf(pa.z - fm)
                                + pb.y*__expf(pb.x - fm) + pb.w*__expf(pb.z - fm);
                sc[rt][r] = __expf(pm[rt][r] - fm) / den;
            }
        __syncthreads();   // partials consumed before attT overwrites s_q
        const int arow = w*16 + ln;
        #pragma unroll
        for (int rt = 0; rt < 4; ++rt) {
            f16x4v pk;
            #pragma unroll
            for (int r = 0; r < 4; ++r) pk[r] = (f16)(accs[rt][r] * sc[rt][r]);
            *(f16x4v*)(s_q + arow*128 + swzb(arow, (rt*16 + g4)*2)) = pk;
        }
    }
    __syncthreads();

    // ---------- Phase D: V=X@WV+vb; in-reg transpose via shfl; XR=attT@V ----
    f32x4 accr[4][4];
    float rinv[4][4];
    {
        f16x8 a2[2][4];
        #pragma unroll
        for (int kc = 0; kc < 2; ++kc)
            #pragma unroll
            for (int rt = 0; rt < 4; ++rt) {
                const int row = rt*16 + ln;
                a2[kc][rt] = *(const f16x8*)(s_q + row*128 + swzb(row, kc*64 + kg16));
            }
        // colsum via ones-MFMA, converted to rinv immediately (frees accONE)
        {
            f16x8 onef;
            #pragma unroll
            for (int i = 0; i < 8; ++i) onef[i] = (f16)1.0f;
            f32x4 accONE[4];
            #pragma unroll
            for (int rt = 0; rt < 4; ++rt) accONE[rt] = (f32x4){0.f,0.f,0.f,0.f};
            #pragma unroll
            for (int kc = 0; kc < 2; ++kc)
                #pragma unroll
                for (int rt = 0; rt < 4; ++rt)
                    accONE[rt] = __builtin_amdgcn_mfma_f32_16x16x32_f16(a2[kc][rt], onef, accONE[rt], 0, 0, 0);
            #pragma unroll
            for (int rt = 0; rt < 4; ++rt)
                #pragma unroll
                for (int r = 0; r < 4; ++r)
                    rinv[rt][r] = __builtin_amdgcn_rcpf(1e-9f + accONE[rt][r]);
        }

        #pragma unroll
        for (int rt = 0; rt < 4; ++rt)
            #pragma unroll
            for (int j = 0; j < 4; ++j) accr[rt][j] = (f32x4){0.f,0.f,0.f,0.f};

        const int sbase = ln + ((lane >> 4) & 1) * 32;   // shfl src base
        const bool hiHalf = (kg >= 2);
        #pragma unroll
        for (int j = 0; j < 4; ++j) {
            const float vb = v_b[(4*w + j)*16 + ln];
            f32x4 accv[4] = {};
            #pragma unroll 2
            for (int kc = 0; kc < 8; ++kc) {
                const f16x8 bf = *(const f16x8*)(ws + (size_t)(112 + kc*16 + 4*w + j)*1024 + lane*16);
                #pragma unroll
                for (int rt = 0; rt < 4; ++rt) {
                    const int row = rt*16 + ln;
                    const f16x8 aX = *(const f16x8*)(s_x + row*512 + swzb(row, kc*64 + kg16));
                    accv[rt] = __builtin_amdgcn_mfma_f32_16x16x32_f16(aX, bf, accv[rt], 0, 0, 0);
                }
            }
            // pack to f16 pairs: pk[rt][p] = samples rt*16+g4+{2p,2p+1}
            u32 pk[4][2];
            #pragma unroll
            for (int rt = 0; rt < 4; ++rt) {
                f16x4v v4;
                #pragma unroll
                for (int r = 0; r < 4; ++r) v4[r] = (f16)(accv[rt][r] + vb);
                const u32x2 p2 = __builtin_bit_cast(u32x2, v4);
                pk[rt][0] = p2.x; pk[rt][1] = p2.y;
            }
            // route: B-frag reg q <- lane (sbase + 16*(q>>1)), pk[2kc+(kg>>1)][q&1]
            #pragma unroll
            for (int kc = 0; kc < 2; ++kc) {
                union { u32 u[4]; f16x8 v; } bu;
                #pragma unroll
                for (int q = 0; q < 4; ++q) {
                    const int srcl = sbase + 16*(q >> 1);
                    const u32 lo = (u32)__shfl((int)pk[2*kc + 0][q & 1], srcl);
                    const u32 hi = (u32)__shfl((int)pk[2*kc + 1][q & 1], srcl);
                    bu.u[q] = hiHalf ? hi : lo;
                }
                #pragma unroll
                for (int rt = 0; rt < 4; ++rt)
                    accr[rt][j] = __builtin_amdgcn_mfma_f32_16x16x32_f16(a2[kc][rt], bu.v, accr[rt][j], 0, 0, 0);
            }
        }
    }
    __syncthreads();  // all waves' X reads done before Y overwrite

    // ---------- D-epilogue: Y = X - XR*rinv (in-place), keep X in regs ------
    f16x4v xsave[4][4];
    #pragma unroll
    for (int j = 0; j < 4; ++j) {
        const int col = (4*w + j)*16 + ln;
        #pragma unroll
        for (int rt = 0; rt < 4; ++rt) {
            f16x4v xs4;
            #pragma unroll
            for (int r = 0; r < 4; ++r) {
                const int row = rt*16 + g4 + r;
                const f16 xv = *(const f16*)(s_x + row*512 + swzb(row, col*2));
                xs4[r] = xv;
                const float yv = (float)xv - accr[rt][j][r] * rinv[rt][r];
                *(f16*)(s_x + row*512 + swzb(row, col*2)) = (f16)yv;
            }
            xsave[j][rt] = xs4;
        }
    }
    __syncthreads();

    // ---------- Phase E: T = Y @ WT + t_b; out = maxpool(X + relu(BN2)) -----
    {
        f32x4 acct[4][4] = {};
        #pragma unroll 2
        for (int kc = 0; kc < 8; ++kc) {
            f16x8 a[4];
            #pragma unroll
            for (int rt = 0; rt < 4; ++rt) {
                const int row = rt*16 + ln;
                a[rt] = *(const f16x8*)(s_x + row*512 + swzb(row, kc*64 + kg16));  // Y
            }
            #pragma unroll
            for (int j = 0; j < 4; ++j) {
                const f16x8 bf = *(const f16x8*)(ws + (size_t)(240 + kc*16 + 4*w + j)*1024 + lane*16);
                #pragma unroll
                for (int rt = 0; rt < 4; ++rt)
                    acct[rt][j] = __builtin_amdgcn_mfma_f32_16x16x32_f16(a[rt], bf, acct[rt][j], 0, 0, 0);
            }
        }
        #pragma unroll
        for (int j = 0; j < 4; ++j) {
            const int col = (4*w + j)*16 + ln;
            const float tb = t_b[col], g2 = bn2g[col]*INVV, b2 = bn2b[col];
            float m = -3.4e38f;
            #pragma unroll
            for (int rt = 0; rt < 4; ++rt)
                #pragma unroll
                for (int r = 0; r < 4; ++r) {
                    const float tv = acct[rt][j][r] + tb;
                    const float rl = fmaxf(tv*g2 + b2, 0.f);
                    const float xv = (float)xsave[j][rt][r];
                    m = fmaxf(m, xv + rl);
                }
            m = fmaxf(m, __shfl_xor(m, 16));
            m = fmaxf(m, __shfl_xor(m, 32));
            if (kg == 0)
                out[((size_t)bb*256 + col)*1024 + s] = m;
        }
    }
}

extern "C" void kernel_launch(void* const* d_in, const int* in_sizes, int n_in,
                              void* d_out, int out_size, void* d_ws, size_t ws_size,
                              hipStream_t stream) {
    (void)in_sizes; (void)n_in; (void)out_size; (void)ws_size;
    unsigned char* ws = (unsigned char*)d_ws;
    prep_kernel<<<92 + 314, 256, 0, stream>>>(
        (const float*)d_in[4],   // mlp_w
        (const float*)d_in[8],   // qk_w
        (const float*)d_in[9],   // v_w
        (const float*)d_in[11],  // t_w
        (const float*)d_in[3],   // up_feature
        ws);
    cloudcrop_mfma<<<2048, 256, 0, stream>>>(
        (const float*)d_in[0],   // seed_xyz
        (const float*)d_in[1],   // pointcloud
        (const float*)d_in[2],   // vp_rot
        (const float*)d_in[5],   // mlp_b
        (const float*)d_in[6],   // bn1_g
        (const float*)d_in[7],   // bn1_b
        (const float*)d_in[10],  // v_b
        (const float*)d_in[12],  // t_b
        (const float*)d_in[13],  // bn2_g
        (const float*)d_in[14],  // bn2_b
        ws,
        (float*)d_out);
}